// Round 9
// baseline (2803.012 us; speedup 1.0000x reference)
//
#include <hip/hip_runtime.h>
#include <math.h>

#define DIM  1024
#define SEQ  64
#define HDIM 256
#define NBLK 256
#define SLOT_STRIDE 32   // 32 u32 = 128 B

typedef float f4 __attribute__((ext_vector_type(4)));

// ---------------- wave / block reduction helpers ----------------
__device__ __forceinline__ float wsum(float v){
  v += __shfl_xor(v, 32, 64); v += __shfl_xor(v, 16, 64); v += __shfl_xor(v, 8, 64);
  v += __shfl_xor(v, 4, 64);  v += __shfl_xor(v, 2, 64);  v += __shfl_xor(v, 1, 64);
  return v;
}
__device__ __forceinline__ float wmax(float v){
  v = fmaxf(v, __shfl_xor(v, 32, 64)); v = fmaxf(v, __shfl_xor(v, 16, 64));
  v = fmaxf(v, __shfl_xor(v, 8, 64));  v = fmaxf(v, __shfl_xor(v, 4, 64));
  v = fmaxf(v, __shfl_xor(v, 2, 64));  v = fmaxf(v, __shfl_xor(v, 1, 64));
  return v;
}
__device__ __forceinline__ float2 breduce2(float va, float vb, float* red){
  int tid = threadIdx.x;
  va = wsum(va); vb = wsum(vb);
  if ((tid & 63) == 0){ red[(tid >> 6) * 2] = va; red[(tid >> 6) * 2 + 1] = vb; }
  __syncthreads();
  float ra = red[0] + red[2] + red[4] + red[6];
  float rb = red[1] + red[3] + red[5] + red[7];
  __syncthreads();
  return make_float2(ra, rb);
}

// ---------------- device-coherent (cross-XCD) payload access ----------------
__device__ __forceinline__ float ldc(const float* p){
  return __hip_atomic_load(p, __ATOMIC_RELAXED, __HIP_MEMORY_SCOPE_AGENT);
}
__device__ __forceinline__ void stc(float* p, float v){
  __hip_atomic_store(p, v, __ATOMIC_RELAXED, __HIP_MEMORY_SCOPE_AGENT);
}

// ---- payload-carrying sync lines: 16B = [p0,p1,p2,epoch], single store/load ----
__device__ __forceinline__ void st_line(float* p, float x, float y, float z, float w){
  f4 v; v.x = x; v.y = y; v.z = z; v.w = w;
  asm volatile("global_store_dwordx4 %0, %1, off sc0 sc1" :: "v"(p), "v"(v) : "memory");
}
__device__ __forceinline__ f4 ld_line(const float* p){
  f4 r;
  asm volatile("global_load_dwordx4 %0, %1, off sc0 sc1\n\ts_waitcnt vmcnt(0)"
               : "=v"(r) : "v"(p) : "memory");
  return r;
}
// poll 4 lines concurrently (1 RTT wall time per round)
__device__ __forceinline__ void poll4(const float* base, int tid, float tgt,
                                      f4& r0, f4& r1, f4& r2, f4& r3){
  const float* p0 = base + (size_t)tid * 32;
  const float* p1 = base + (size_t)(tid + 256) * 32;
  const float* p2 = base + (size_t)(tid + 512) * 32;
  const float* p3 = base + (size_t)(tid + 768) * 32;
  unsigned spins = 0;
  for (;;){
    asm volatile(
      "global_load_dwordx4 %0, %4, off sc0 sc1\n\t"
      "global_load_dwordx4 %1, %5, off sc0 sc1\n\t"
      "global_load_dwordx4 %2, %6, off sc0 sc1\n\t"
      "global_load_dwordx4 %3, %7, off sc0 sc1\n\t"
      "s_waitcnt vmcnt(0)"
      : "=&v"(r0), "=&v"(r1), "=&v"(r2), "=&v"(r3)
      : "v"(p0), "v"(p1), "v"(p2), "v"(p3)
      : "memory");
    if (r0.w >= tgt && r1.w >= tgt && r2.w >= tgt && r3.w >= tgt) return;
    if (++spins > 100000000u) return;   // safety valve
  }
}
__device__ __forceinline__ f4 poll1(const float* p, float tgt){
  unsigned spins = 0;
  for (;;){
    f4 r = ld_line(p);
    if (r.w >= tgt) return r;
    if (++spins > 100000000u) return r;
  }
}

__device__ __forceinline__ void spin_ge(unsigned* p, unsigned ep){
  unsigned spins = 0;
  while (__hip_atomic_load(p, __ATOMIC_RELAXED, __HIP_MEMORY_SCOPE_AGENT) < ep){
    if (++spins > 4194304u){
      unsigned s2 = 0;
      while (__hip_atomic_load(p, __ATOMIC_ACQUIRE, __HIP_MEMORY_SCOPE_AGENT) < ep){
        __builtin_amdgcn_s_sleep(2);
        if (++s2 > 100000000u) break;
      }
      return;
    }
  }
}
// classic barrier, used only for the 3 P-stages
__device__ __forceinline__ void gsync(unsigned* slots, unsigned ep, int bid, int tid){
  asm volatile("s_waitcnt vmcnt(0)" ::: "memory");
  __syncthreads();
  if (tid == 0)
    __hip_atomic_store(&slots[bid * SLOT_STRIDE], ep, __ATOMIC_RELAXED, __HIP_MEMORY_SCOPE_AGENT);
  spin_ge(&slots[tid * SLOT_STRIDE], ep);
  __syncthreads();
  asm volatile("" ::: "memory");
}

// ---------------- Cm = vm_w @ vr_w (only remaining prologue kernel) ----------------
__global__ void matmul_nn_1024(const float* __restrict__ A, const float* __restrict__ B,
                               float* __restrict__ Cc){
  __shared__ float As[32][33];
  __shared__ float Bs[32][33];
  int tb = blockIdx.x * 32, ta = blockIdx.y * 32;
  int tx = threadIdx.x & 31, ty = threadIdx.x >> 5;
  float acc[4] = {0.f, 0.f, 0.f, 0.f};
  for (int k0 = 0; k0 < 1024; k0 += 32){
    for (int r = ty; r < 32; r += 8) As[r][tx] = A[(size_t)(ta + r) * 1024 + k0 + tx];
    for (int r = ty; r < 32; r += 8) Bs[r][tx] = B[(size_t)(k0 + r) * 1024 + tb + tx];
    __syncthreads();
    #pragma unroll
    for (int kk = 0; kk < 32; ++kk){
      float bv = Bs[kk][tx];
      #pragma unroll
      for (int m = 0; m < 4; ++m) acc[m] = fmaf(As[ty + 8 * m][kk], bv, acc[m]);
    }
    __syncthreads();
  }
  for (int m = 0; m < 4; ++m) Cc[(size_t)(ta + ty + 8 * m) * 1024 + tb + tx] = acc[m];
}

// ---------------- the persistent autoregressive decode ----------------
struct CoopArgs {
  const float *hs, *hid_w, *hid_b;
  const float *sa_in_w, *sa_in_b, *sa_out_w, *sa_out_b;
  const float *ca_in_w, *ca_in_b, *ca_out_w, *ca_out_b;
  const float *ln1_g, *ln1_b, *ln2_g, *ln2_b, *ln3_g, *ln3_b;
  const float *ff1_w, *ff1_b, *ff2_w, *ff2_b;
  const float *vr_w, *vr_b, *vm_w, *vm_b, *obj_w;
  const float *Cm;
  float *mem, *vtmp, *cac, *kc;
  float *lS1, *lU, *lH, *lW, *lE, *lSC;   // payload line regions (128B lines)
  float *out;
  unsigned *bar;
};

__global__ void __launch_bounds__(256, 2) decode_loop(CoopArgs a){
  const int tid = threadIdx.x, bid = blockIdx.x;
  const int wave = tid >> 6, lane = tid & 63;
  const int gw = bid * 4 + wave;            // global wave id / row, 0..1023
  __shared__ float smA[2048];
  __shared__ float smB[1024];
  __shared__ float smC[1024];
  __shared__ float scp[256];
  __shared__ float red[8];
  unsigned ep = 0;

  // pe-on-the-fly constants for this thread's 4 dims
  const float NLOG = -9.210340371976184f / 1024.0f;   // -ln(10000)/D
  float div4[4]; int par4[4];
  #pragma unroll
  for (int k = 0; k < 4; ++k){
    int d = tid + 256 * k;
    div4[k] = __expf((float)(2 * (d >> 1)) * NLOG);
    par4[k] = d & 1;
  }

  // ======== P-stages (classic barrier; each wave covers ALL 64 t) ========
  // P1: mem[t][gw] = hid_w[gw].hs[t] + hid_b[gw]
  {
    float pw[16];
    const float* pr = a.hid_w + (size_t)gw * DIM;
    #pragma unroll
    for (int k = 0; k < 16; ++k) pw[k] = pr[lane + 64 * k];
    float bias = a.hid_b[gw];
    for (int t = 0; t < 64; ++t){
      const float* xr = a.hs + (size_t)t * DIM;
      float acc = 0.f;
      #pragma unroll
      for (int k = 0; k < 16; ++k) acc = fmaf(pw[k], xr[lane + 64 * k], acc);
      acc = wsum(acc);
      if (lane == 0) stc(a.mem + (size_t)t * DIM + gw, acc + bias);
    }
  }
  ++ep; gsync(a.bar, ep, bid, tid);

  // P2: vtmp[t][gw] = ca_wv[gw].mem[t] + ca_bv[gw]
  {
    float pw[16];
    const float* pr = a.ca_in_w + (size_t)(2 * DIM + gw) * DIM;
    #pragma unroll
    for (int k = 0; k < 16; ++k) pw[k] = pr[lane + 64 * k];
    float bias = a.ca_in_b[2 * DIM + gw];
    for (int t = 0; t < 64; ++t){
      const float* xr = a.mem + (size_t)t * DIM;
      #pragma unroll
      for (int k = 0; k < 4; ++k) smA[tid + 256 * k] = ldc(xr + tid + 256 * k);
      __syncthreads();
      float acc = 0.f;
      #pragma unroll
      for (int k = 0; k < 16; ++k) acc = fmaf(pw[k], smA[lane + 64 * k], acc);
      acc = wsum(acc);
      if (lane == 0) stc(a.vtmp + (size_t)t * DIM + gw, acc + bias);
      __syncthreads();
    }
  }
  ++ep; gsync(a.bar, ep, bid, tid);

  // P3: cac[t][gw] = ca_out_w[gw].vtmp[t] + ca_out_b[gw]
  {
    float pw[16];
    const float* pr = a.ca_out_w + (size_t)gw * DIM;
    #pragma unroll
    for (int k = 0; k < 16; ++k) pw[k] = pr[lane + 64 * k];
    float bias = a.ca_out_b[gw];
    for (int t = 0; t < 64; ++t){
      const float* xr = a.vtmp + (size_t)t * DIM;
      #pragma unroll
      for (int k = 0; k < 4; ++k) smA[tid + 256 * k] = ldc(xr + tid + 256 * k);
      __syncthreads();
      float acc = 0.f;
      #pragma unroll
      for (int k = 0; k < 16; ++k) acc = fmaf(pw[k], smA[lane + 64 * k], acc);
      acc = wsum(acc);
      if (lane == 0) stc(a.cac + (size_t)t * DIM + gw, acc + bias);
      __syncthreads();
    }
  }
  ++ep; gsync(a.bar, ep, bid, tid);

  // ---- main weight rows into registers (128 floats/thread)
  float wq[16], wk[16], wv[16], wo[16], f1a[16], f1b[16], f2[32];
  {
    const float* pq = a.sa_in_w + (size_t)gw * DIM;
    const float* pk = a.sa_in_w + (size_t)(DIM + gw) * DIM;
    const float* pv = a.sa_in_w + (size_t)(2 * DIM + gw) * DIM;
    const float* po = a.sa_out_w + (size_t)gw * DIM;
    const float* p1a = a.ff1_w + (size_t)(2 * gw) * DIM;
    const float* p1b = a.ff1_w + (size_t)(2 * gw + 1) * DIM;
    const float* p2 = a.ff2_w + (size_t)gw * 2048;
    #pragma unroll
    for (int k = 0; k < 16; ++k){
      int d = lane + 64 * k;
      wq[k] = pq[d]; wk[k] = pk[d]; wv[k] = pv[d]; wo[k] = po[d];
      f1a[k] = p1a[d]; f1b[k] = p1b[d];
    }
    #pragma unroll
    for (int k = 0; k < 32; ++k) f2[k] = p2[lane + 64 * k];
  }
  const float b_q  = a.sa_in_b[gw];
  const float b_k  = a.sa_in_b[DIM + gw];
  const float b_v  = a.sa_in_b[2 * DIM + gw];
  const float b_o  = a.sa_out_b[gw];
  const float b_1a = a.ff1_b[2 * gw];
  const float b_1b = a.ff1_b[2 * gw + 1];
  const float b_2  = a.ff2_b[gw];
  const float b_vr = a.vr_b[gw];
  float cbv;
  {
    const float* pv = a.vm_w + (size_t)gw * DIM;
    float acc = 0.f;
    #pragma unroll
    for (int k = 0; k < 16; ++k) acc = fmaf(pv[lane + 64 * k], a.vr_b[lane + 64 * k], acc);
    cbv = wsum(acc) + a.vm_b[gw] + a.obj_w[(size_t)gw * 80];
  }

  // running projected-V cache: lane j holds c^h_j = wo_gw[head h] . V_j[head h]
  float c0 = 0.f, c1 = 0.f, c2 = 0.f, c3 = 0.f;

  const bool is_score = (bid < 16);
  const int sc_h  = bid >> 2;
  const int sc_jg = bid & 3;
  const int swid  = bid * 4 + wave;                    // 0..63 for score blocks
  const float sc_slope = 1.0f / (float)(4 << (2 * sc_h));

  for (int i = 0; i < SEQ; ++i){
    const float posf = (float)(i % 30);
    const float epf  = (float)(i + 1);
    float remb;

    // ---- S1: stage x = emb[i]+pe[i]; QKV; publish (q,k,v) line; kc row i
    {
      if (i == 0){
        #pragma unroll
        for (int k = 0; k < 4; ++k){
          int d = tid + 256 * k;
          float arg = posf * div4[k];
          float pe = par4[k] ? cosf(arg) : sinf(arg);
          smA[d] = a.obj_w[(size_t)d * 80] + pe;
        }
      } else {
        f4 r0, r1, r2, r3;
        poll4(a.lE, tid, (float)i, r0, r1, r2, r3);
        float ev[4] = {r0.x, r1.x, r2.x, r3.x};
        #pragma unroll
        for (int k = 0; k < 4; ++k){
          int d = tid + 256 * k;
          float arg = posf * div4[k];
          float pe = par4[k] ? cosf(arg) : sinf(arg);
          smA[d] = ev[k] + pe;
        }
      }
      __syncthreads();
      remb = smA[gw];                      // residual (= emb+pe at dim gw)
      float aq = 0.f, ak = 0.f, av = 0.f;
      #pragma unroll
      for (int k = 0; k < 16; ++k){
        float x = smA[lane + 64 * k];
        aq = fmaf(wq[k], x, aq);
        ak = fmaf(wk[k], x, ak);
        av = fmaf(wv[k], x, av);
      }
      aq = wsum(aq); ak = wsum(ak); av = wsum(av);
      if (lane == 0){
        stc(a.kc + (size_t)i * DIM + gw, ak + b_k);     // K cache for future iters
        asm volatile("s_waitcnt vmcnt(0)" ::: "memory"); // drain before line store
        st_line(a.lS1 + (size_t)gw * 32, aq + b_q, ak + b_k, av + b_v, epf);
      }
    }

    // ---- S2: poll qkv lines; c-update; scores (16 blocks); softmax; u line
    {
      f4 r0, r1, r2, r3;
      poll4(a.lS1, tid, epf, r0, r1, r2, r3);
      smB[tid] = r0.z; smB[tid + 256] = r1.z; smB[tid + 512] = r2.z; smB[tid + 768] = r3.z; // V row
      smC[tid] = r0.x; smC[tid + 256] = r1.x; smC[tid + 512] = r2.x; smC[tid + 768] = r3.x; // q row
      __syncthreads();
      // c-update from V row
      float p0 = 0.f, p1 = 0.f, p2 = 0.f, p3 = 0.f;
      #pragma unroll
      for (int k = 0; k < 4; ++k){
        p0 = fmaf(wo[k],      smB[lane + 64 * k],        p0);
        p1 = fmaf(wo[k + 4],  smB[lane + 64 * (k + 4)],  p1);
        p2 = fmaf(wo[k + 8],  smB[lane + 64 * (k + 8)],  p2);
        p3 = fmaf(wo[k + 12], smB[lane + 64 * (k + 12)], p3);
      }
      p0 = wsum(p0); p1 = wsum(p1); p2 = wsum(p2); p3 = wsum(p3);
      if (lane == i){ c0 = p0; c1 = p1; c2 = p2; c3 = p3; }
      // scores (block-uniform branch)
      if (is_score){
        float sj[4];
        #pragma unroll
        for (int jj = 0; jj < 4; ++jj){
          int j = sc_jg * 16 + wave * 4 + jj;
          if (j <= i){
            const float* kr = a.kc + (size_t)j * DIM + sc_h * HDIM;
            float acc = 0.f;
            #pragma unroll
            for (int m = 0; m < 4; ++m)
              acc = fmaf(smC[sc_h * HDIM + m * 64 + lane], ldc(kr + m * 64 + lane), acc);
            acc = wsum(acc);
            sj[jj] = acc * 0.0625f - sc_slope * (float)((i - j) / 30);
          } else sj[jj] = 0.f;
        }
        if (lane == 0){
          st_line(a.lSC + (size_t)(swid * 2) * 32,     sj[0], sj[1], 0.f, epf);
          st_line(a.lSC + (size_t)(swid * 2 + 1) * 32, sj[2], sj[3], 0.f, epf);
        }
      }
      if (tid < 128){
        f4 r = poll1(a.lSC + (size_t)tid * 32, epf);
        int sw = tid >> 1, half = tid & 1;
        int sb = sw >> 2, wv2 = sw & 3;
        int h = sb >> 2, jg = sb & 3;
        int j0 = jg * 16 + wv2 * 4 + half * 2;
        scp[h * 64 + j0] = r.x; scp[h * 64 + j0 + 1] = r.y;
      }
      __syncthreads();
      // softmax (wave = head; wave owns its scp row)
      {
        const int h = wave;
        float sv = (lane <= i) ? scp[h * 64 + lane] : -3.0e38f;
        float mx = wmax(sv);
        float p = (lane <= i) ? __expf(sv - mx) : 0.f;
        float sum = wsum(p);
        scp[h * 64 + lane] = p / sum;
      }
      __syncthreads();
      float t = scp[lane] * c0 + scp[64 + lane] * c1 + scp[128 + lane] * c2 + scp[192 + lane] * c3;
      t = wsum(t);
      if (lane == 0) st_line(a.lU + (size_t)gw * 32, remb + t + b_o, 0.f, 0.f, epf);
    }

    // ---- S3: poll u; ln1 -> +cac -> ln2; ff1 -> hb line
    float x2v;
    {
      float cr[4];
      #pragma unroll
      for (int k = 0; k < 4; ++k) cr[k] = ldc(a.cac + (size_t)i * DIM + tid + 256 * k);
      f4 r0, r1, r2, r3;
      poll4(a.lU, tid, epf, r0, r1, r2, r3);
      smA[tid] = r0.x; smA[tid + 256] = r1.x; smA[tid + 512] = r2.x; smA[tid + 768] = r3.x;
      __syncthreads();
      float sa = 0.f, sb = 0.f;
      #pragma unroll
      for (int k = 0; k < 4; ++k){ float x = smA[tid + 256 * k]; sa += x; sb = fmaf(x, x, sb); }
      float2 r = breduce2(sa, sb, red);
      float mean = r.x * (1.f / 1024.f);
      float var  = r.y * (1.f / 1024.f) - mean * mean;
      float rs = 1.f / sqrtf(var + 1e-5f);
      float tv[4];
      float ta = 0.f, tb = 0.f;
      #pragma unroll
      for (int k = 0; k < 4; ++k){
        int d = tid + 256 * k;
        float x1 = (smA[d] - mean) * rs * a.ln1_g[d] + a.ln1_b[d];
        tv[k] = x1 + cr[k];
        ta += tv[k]; tb = fmaf(tv[k], tv[k], tb);
      }
      float2 r2v = breduce2(ta, tb, red);
      float mean2 = r2v.x * (1.f / 1024.f);
      float var2  = r2v.y * (1.f / 1024.f) - mean2 * mean2;
      float rs2 = 1.f / sqrtf(var2 + 1e-5f);
      #pragma unroll
      for (int k = 0; k < 4; ++k){
        int d = tid + 256 * k;
        smA[d] = (tv[k] - mean2) * rs2 * a.ln2_g[d] + a.ln2_b[d];
      }
      __syncthreads();
      x2v = smA[gw];
      float acc0 = 0.f, acc1 = 0.f;
      #pragma unroll
      for (int k = 0; k < 16; ++k){
        float x = smA[lane + 64 * k];
        acc0 = fmaf(f1a[k], x, acc0);
        acc1 = fmaf(f1b[k], x, acc1);
      }
      acc0 = wsum(acc0); acc1 = wsum(acc1);
      if (lane == 0)
        st_line(a.lH + (size_t)gw * 32, fmaxf(acc0 + b_1a, 0.f), fmaxf(acc1 + b_1b, 0.f), 0.f, epf);
    }

    // ---- S4: poll hb; ff2 -> w line ; prefetch vr_w/Cm rows
    float vrr[16], cmr[16];
    {
      const float* pr = a.vr_w + (size_t)gw * DIM;
      const float* pc = a.Cm + (size_t)gw * DIM;
      #pragma unroll
      for (int k = 0; k < 16; ++k){ vrr[k] = pr[lane + 64 * k]; cmr[k] = pc[lane + 64 * k]; }
      f4 r0, r1, r2, r3;
      poll4(a.lH, tid, epf, r0, r1, r2, r3);
      smA[2 * tid] = r0.x;           smA[2 * tid + 1] = r0.y;
      smA[2 * (tid + 256)] = r1.x;   smA[2 * (tid + 256) + 1] = r1.y;
      smA[2 * (tid + 512)] = r2.x;   smA[2 * (tid + 512) + 1] = r2.y;
      smA[2 * (tid + 768)] = r3.x;   smA[2 * (tid + 768) + 1] = r3.y;
      __syncthreads();
      float acc = 0.f;
      #pragma unroll
      for (int k = 0; k < 32; ++k) acc = fmaf(f2[k], smA[lane + 64 * k], acc);
      acc = wsum(acc);
      if (lane == 0) st_line(a.lW + (size_t)gw * 32, x2v + acc + b_2, 0.f, 0.f, epf);
    }

    // ---- S5: poll w; ln3; out row i; recurrence -> emb line
    {
      f4 r0, r1, r2, r3;
      poll4(a.lW, tid, epf, r0, r1, r2, r3);
      smA[tid] = r0.x; smA[tid + 256] = r1.x; smA[tid + 512] = r2.x; smA[tid + 768] = r3.x;
      __syncthreads();
      float sa = 0.f, sb = 0.f;
      #pragma unroll
      for (int k = 0; k < 4; ++k){ float x = smA[tid + 256 * k]; sa += x; sb = fmaf(x, x, sb); }
      float2 r = breduce2(sa, sb, red);
      float mean = r.x * (1.f / 1024.f);
      float var  = r.y * (1.f / 1024.f) - mean * mean;
      float rs = 1.f / sqrtf(var + 1e-5f);
      float ov[4];
      #pragma unroll
      for (int k = 0; k < 4; ++k){
        int d = tid + 256 * k;
        ov[k] = (smA[d] - mean) * rs * a.ln3_g[d] + a.ln3_b[d];
      }
      __syncthreads();
      #pragma unroll
      for (int k = 0; k < 4; ++k) smA[tid + 256 * k] = ov[k];
      __syncthreads();
      float ar = 0.f, ac = 0.f;
      #pragma unroll
      for (int k = 0; k < 16; ++k){
        float x = smA[lane + 64 * k];
        ar = fmaf(vrr[k], x, ar);
        ac = fmaf(cmr[k], x, ac);
      }
      ar = wsum(ar); ac = wsum(ac);
      if (lane == 0){
        a.out[(size_t)i * DIM + gw] = ar + b_vr;
        st_line(a.lE + (size_t)gw * 32, ac + cbv, 0.f, 0.f, epf);
      }
    }
  }
}

// ---------------- host launcher ----------------
extern "C" void kernel_launch(void* const* d_in, const int* in_sizes, int n_in,
                              void* d_out, int out_size, void* d_ws, size_t ws_size,
                              hipStream_t stream){
  const float* hs       = (const float*)d_in[0];
  const float* hid_w    = (const float*)d_in[1];
  const float* hid_b    = (const float*)d_in[2];
  const float* obj_w    = (const float*)d_in[3];
  const float* sa_in_w  = (const float*)d_in[4];
  const float* sa_in_b  = (const float*)d_in[5];
  const float* sa_out_w = (const float*)d_in[6];
  const float* sa_out_b = (const float*)d_in[7];
  const float* ca_in_w  = (const float*)d_in[8];
  const float* ca_in_b  = (const float*)d_in[9];
  const float* ca_out_w = (const float*)d_in[10];
  const float* ca_out_b = (const float*)d_in[11];
  const float* ln1_g    = (const float*)d_in[12];
  const float* ln1_b    = (const float*)d_in[13];
  const float* ln2_g    = (const float*)d_in[14];
  const float* ln2_b    = (const float*)d_in[15];
  const float* ln3_g    = (const float*)d_in[16];
  const float* ln3_b    = (const float*)d_in[17];
  const float* ff1_w    = (const float*)d_in[18];
  const float* ff1_b    = (const float*)d_in[19];
  const float* ff2_w    = (const float*)d_in[20];
  const float* ff2_b    = (const float*)d_in[21];
  const float* vr_w     = (const float*)d_in[22];
  const float* vr_b     = (const float*)d_in[23];
  const float* vm_w     = (const float*)d_in[24];
  const float* vm_b     = (const float*)d_in[25];

  float* ws = (float*)d_ws;
  float* mem  = ws;                 // 65536
  float* vtmp = ws + 65536;         // 65536
  float* cac  = ws + 131072;        // 65536
  float* kc   = ws + 196608;        // 65536
  float* Cm   = ws + 262144;        // 1048576
  float* lS1  = ws + 1310720;       // 1024 lines * 32 floats = 32768
  float* lU   = ws + 1343488;       // 32768
  float* lH   = ws + 1376256;       // 32768
  float* lW   = ws + 1409024;       // 32768
  float* lE   = ws + 1441792;       // 32768
  float* lSC  = ws + 1474560;       // 128 lines * 32 = 4096
  unsigned* bar = (unsigned*)(ws + 1478656);   // 256*32 u32 = 8192 u32

  // zero all line regions + P-stage barrier slots (re-poison safe)
  hipMemsetAsync((void*)lS1, 0, (size_t)(167936 + 8192) * 4, stream);

  // Cm = vm_w @ vr_w  (folds the two recurrence gemvs)
  matmul_nn_1024<<<dim3(32, 32), 256, 0, stream>>>(vm_w, vr_w, Cm);

  CoopArgs A;
  A.hs = hs; A.hid_w = hid_w; A.hid_b = hid_b;
  A.sa_in_w = sa_in_w; A.sa_in_b = sa_in_b; A.sa_out_w = sa_out_w; A.sa_out_b = sa_out_b;
  A.ca_in_w = ca_in_w; A.ca_in_b = ca_in_b; A.ca_out_w = ca_out_w; A.ca_out_b = ca_out_b;
  A.ln1_g = ln1_g; A.ln1_b = ln1_b; A.ln2_g = ln2_g; A.ln2_b = ln2_b; A.ln3_g = ln3_g; A.ln3_b = ln3_b;
  A.ff1_w = ff1_w; A.ff1_b = ff1_b; A.ff2_w = ff2_w; A.ff2_b = ff2_b;
  A.vr_w = vr_w; A.vr_b = vr_b; A.vm_w = vm_w; A.vm_b = vm_b; A.obj_w = obj_w;
  A.Cm = Cm;
  A.mem = mem; A.vtmp = vtmp; A.cac = cac; A.kc = kc;
  A.lS1 = lS1; A.lU = lU; A.lH = lH; A.lW = lW; A.lE = lE; A.lSC = lSC;
  A.out = (float*)d_out;
  A.bar = bar;

  void* params[1] = { &A };
  hipError_t e = hipLaunchCooperativeKernel((void*)decode_loop, dim3(NBLK), dim3(256), params, 0, stream);
  if (e != hipSuccess){
    decode_loop<<<dim3(NBLK), dim3(256), 0, stream>>>(A);
  }
}